// Round 4
// baseline (261.919 us; speedup 1.0000x reference)
//
#include <hip/hip_runtime.h>
#include <hip/hip_bf16.h>
#include <cfloat>

// VQ-VAE vector quantizer.  N=262144 rows x D=100, K=512 codes.
// out[0..N*D-1] = quantized (fp32-exact gather); out[N*D]=mse; out[N*D+1]=0.25*mse.
//
// R9: whole-codebook-in-LDS, barrier-free decorrelated waves.
//  Post-mortem R5-R8: dur pinned at 104-114us regardless of block size /
//  barrier structure; ~85% of wave residency is stalled and the per-chunk
//  __syncthreads keeps all waves phase-locked (stalls overlap instead of
//  interleaving).  R6 proved barrier-free + L2-latency B loads is worse.
//  R9 = barrier-free + LDS-latency B loads:
//   - stage ALL 16 chunks (128 KB) + e2 (2 KB) into LDS once, ONE barrier
//   - main loop: zero barriers; B via conflict-free lane-linear ds_read_b128
//     from the resident codebook; compiler free to pipeline across chunks
//   - per-WAVE epilogue: widx written+read by the same wave (lgkmcnt(0) only,
//     no block sync); per-wave atomicAdd into ws[wave] (8 slots, low contention)
//   - math/chunk order bitwise-identical to R8
//  LDS 132 KB => 1 block/CU (8 decorrelated waves).  R7 proved >64KB static ok.
//  Tripwires: VGPR 84-120 (not 64); WRITE_SIZE exactly 102416; conflicts ~0.
//
// ws: ws_f[0..7] = per-wave-slot loss accum; ws_f[16..528) = e2[k] (fp32);
//     bytes [4096..4096+131072): bf16 cb; chunk c granule layout (16B granules):
//     granule g = (s*2+tt)*64 + quad*16 + lr  holds code (c*32+tt*16+lr),
//     k = s*32+quad*8+{0..7}  (zero-padded for k>=100).

#define N_ROWS (64 * 64 * 64)
#define D 100
#define KCODES 512
#define CB_OFF 4096
#define E2_OFF 16

typedef __attribute__((ext_vector_type(8))) short short8;
typedef __attribute__((ext_vector_type(4))) float f32x4;

__device__ __forceinline__ unsigned short f2bf(float f) {
    union { float f; unsigned u; } v; v.f = f;
    unsigned r = v.u + 0x7FFF + ((v.u >> 16) & 1);   // RNE
    return (unsigned short)(r >> 16);
}
__device__ __forceinline__ unsigned pk2(float a, float b) {   // packed bf16 cvt (RNE)
    union { __hip_bfloat162 h; unsigned u; } c;
    c.h = __float22bfloat162_rn(make_float2(a, b));
    return c.u;
}
__device__ __forceinline__ short8 pack8(const float4& a, const float4& b) {
    union { unsigned u[4]; short8 v; } r;
    r.u[0] = pk2(a.x, a.y); r.u[1] = pk2(a.z, a.w);
    r.u[2] = pk2(b.x, b.y); r.u[3] = pk2(b.z, b.w);
    return r.v;
}

// ---- init: one wave per code ----
__global__ __launch_bounds__(64) void vq_init(const float* __restrict__ emb,
                                              float* __restrict__ ws) {
    const int code = blockIdx.x, l = threadIdx.x;
    const float* e = emb + code * D;
    if (code == 0 && l < 8) ws[l] = 0.0f;          // 8 per-wave-slot loss accums
    float a = e[l];
    float b = (l < D - 64) ? e[64 + l] : 0.0f;
    float p = fmaf(a, a, b * b);
#pragma unroll
    for (int off = 32; off; off >>= 1) p += __shfl_xor(p, off);
    if (l == 0) ws[E2_OFF + code] = p;

    // cb granules: 16 per code, written by lanes 0..15 (8 shorts each)
    if (l < 16) {
        const int s = l >> 2, q = l & 3;
        short8 v;
#pragma unroll
        for (int j = 0; j < 8; ++j) {
            int k = s * 32 + q * 8 + j;
            v[j] = (k < D) ? (short)f2bf(e[k]) : (short)0;
        }
        const int chunk = code >> 5, ci = code & 31;
        const int tt = ci >> 4, lr = ci & 15;
        unsigned short* cb = (unsigned short*)((char*)ws + CB_OFF);
        // short offset = chunk*4096 + granule*8, granule = (s*2+tt)*64 + q*16 + lr
        *(short8*)(cb + chunk * 4096 + ((s * 2 + tt) * 64 + q * 16 + lr) * 8) = v;
    }
}

// ---- main: 8 waves/block, 64 rows/wave (M=4), whole codebook in LDS ----
__global__ __launch_bounds__(512, 2) void vq_main(const float* __restrict__ x,
                                                  const float* __restrict__ emb,
                                                  float* __restrict__ ws,
                                                  float* __restrict__ out) {
    __shared__ uint4  sbuf[8192];     // 128 KB: the WHOLE codebook (16 chunks)
    __shared__ float  e2s[KCODES];    // 2 KB
    __shared__ int    widx[512];      // 2 KB (per-wave regions)

    const int tid = threadIdx.x, wave = tid >> 6, lane = tid & 63;
    const int quad = lane >> 4, lr = lane & 15;
    const long brow = (long)blockIdx.x * 512;
    const long wrow = brow + wave * 64;

    // ---- A: 28 independent scattered loads (batched), then convert ----
    float4 av[4][7];
#pragma unroll
    for (int m = 0; m < 4; ++m) {
        const float* xr = x + (wrow + m * 16 + lr) * D + quad * 8;
        av[m][0] = *(const float4*)(xr);
        av[m][1] = *(const float4*)(xr + 4);
        av[m][2] = *(const float4*)(xr + 32);
        av[m][3] = *(const float4*)(xr + 36);
        av[m][4] = *(const float4*)(xr + 64);
        av[m][5] = *(const float4*)(xr + 68);
        av[m][6] = *(const float4*)(x + (wrow + m * 16 + lr) * D + 96);  // same addr all quads
    }

    // ---- stage the whole codebook + e2 (L2-resident; overlaps A latency) ----
    const uint4* __restrict__ cbg = (const uint4*)((const char*)ws + CB_OFF);
    const float* __restrict__ e2g = ws + E2_OFF;
#pragma unroll
    for (int kk = 0; kk < 16; kk += 4) {        // 4 in flight: bounded reg cost
        uint4 t0 = cbg[(kk + 0) * 512 + tid];
        uint4 t1 = cbg[(kk + 1) * 512 + tid];
        uint4 t2 = cbg[(kk + 2) * 512 + tid];
        uint4 t3 = cbg[(kk + 3) * 512 + tid];
        sbuf[(kk + 0) * 512 + tid] = t0;
        sbuf[(kk + 1) * 512 + tid] = t1;
        sbuf[(kk + 2) * 512 + tid] = t2;
        sbuf[(kk + 3) * 512 + tid] = t3;
    }
    e2s[tid] = e2g[tid];

    // ---- convert A -> fragments + fp32 norms ----
    short8 A[4][4];
    float  xnorm[4];
#pragma unroll
    for (int m = 0; m < 4; ++m) {
        float4 z = av[m][6];
        if (quad != 0) z = make_float4(0.f, 0.f, 0.f, 0.f);   // tail only in quad 0
        float nrm = 0.f;
#pragma unroll
        for (int i = 0; i < 6; ++i) {
            float4 f = av[m][i];
            nrm = fmaf(f.x, f.x, nrm); nrm = fmaf(f.y, f.y, nrm);
            nrm = fmaf(f.z, f.z, nrm); nrm = fmaf(f.w, f.w, nrm);
        }
        nrm = fmaf(z.x, z.x, nrm); nrm = fmaf(z.y, z.y, nrm);
        nrm = fmaf(z.z, z.z, nrm); nrm = fmaf(z.w, z.w, nrm);
        A[m][0] = pack8(av[m][0], av[m][1]);
        A[m][1] = pack8(av[m][2], av[m][3]);
        A[m][2] = pack8(av[m][4], av[m][5]);
        A[m][3] = pack8(z, make_float4(0.f, 0.f, 0.f, 0.f));
        nrm += __shfl_xor(nrm, 16);
        nrm += __shfl_xor(nrm, 32);
        xnorm[m] = nrm;
    }

    __syncthreads();     // the ONLY block-wide barrier: codebook + e2 visible

    float    runmin[4][4];
    unsigned runidx[4][4];
#pragma unroll
    for (int m = 0; m < 4; ++m)
#pragma unroll
        for (int r = 0; r < 4; ++r) { runmin[m][r] = FLT_MAX; runidx[m][r] = 0; }

    const short8* __restrict__ sbl = (const short8*)sbuf;   // 8192 granules

    for (int c = 0; c < 16; ++c) {
        // B fragments: lane-linear ds_read_b128, conflict-free (R5-proven)
        short8 B[2][4];
#pragma unroll
        for (int s = 0; s < 4; ++s) {
            B[0][s] = sbl[c * 512 + (s * 2 + 0) * 64 + lane];
            B[1][s] = sbl[c * 512 + (s * 2 + 1) * 64 + lane];
        }
        float e2v0 = e2s[c * 32 + lr];
        float e2v1 = e2s[c * 32 + 16 + lr];

        f32x4 acc[4][2];
#pragma unroll
        for (int m = 0; m < 4; ++m) {
            acc[m][0] = (f32x4){0.f, 0.f, 0.f, 0.f};
            acc[m][1] = (f32x4){0.f, 0.f, 0.f, 0.f};
        }
#pragma unroll
        for (int s = 0; s < 4; ++s)
#pragma unroll
            for (int m = 0; m < 4; ++m) {
                acc[m][0] = __builtin_amdgcn_mfma_f32_16x16x32_bf16(A[m][s], B[0][s], acc[m][0], 0, 0, 0);
                acc[m][1] = __builtin_amdgcn_mfma_f32_16x16x32_bf16(A[m][s], B[1][s], acc[m][1], 0, 0, 0);
            }

        // fold: score = e2 - 2<x,e>; C layout row=quad*4+r, col=lr
#pragma unroll
        for (int m = 0; m < 4; ++m)
#pragma unroll
            for (int tt = 0; tt < 2; ++tt) {
                float e2v = tt ? e2v1 : e2v0;
                unsigned code = c * 32 + tt * 16 + lr;
#pragma unroll
                for (int r = 0; r < 4; ++r) {
                    float sc = fmaf(-2.0f, acc[m][tt][r], e2v);
                    if (sc < runmin[m][r]) { runmin[m][r] = sc; runidx[m][r] = code; }
                }
            }
    }

    // ---- per-row argmin across the 16 columns (xor 8,4,2,1 stays in quad) ----
    float lsum = 0.0f;
#pragma unroll
    for (int m = 0; m < 4; ++m)
#pragma unroll
        for (int r = 0; r < 4; ++r) {
            float    s = runmin[m][r];
            unsigned i = runidx[m][r];
#pragma unroll
            for (int off = 8; off >= 1; off >>= 1) {
                float    os = __shfl_xor(s, off);
                unsigned oi = (unsigned)__shfl_xor((int)i, off);
                if (os < s || (os == s && oi < i)) { s = os; i = oi; }
            }
            if (lr == quad * 4 + r) {                  // writer lane for this row
                lsum += xnorm[m] + s;                  // ||x||^2 + e2 - 2<x,e>
                widx[wave * 64 + m * 16 + quad * 4 + r] = (int)i;
            }
        }
#pragma unroll
    for (int off = 32; off >= 1; off >>= 1) lsum += __shfl_xor(lsum, off);
    if (lane == 0) atomicAdd(&ws[wave], lsum);         // per-wave slot, 8-way spread

    // within-wave LDS visibility only: no block barrier needed
    asm volatile("s_waitcnt lgkmcnt(0)" ::: "memory");

    // ---- per-WAVE coalesced epilogue: 1600 float4 = 64 rows x 25, 5-deep ----
    const float4* __restrict__ ef = (const float4*)emb;   // 25 float4 per row, exact
    float4* __restrict__ og = (float4*)(out + wrow * D);  // this wave's 64 rows
    const int rbase = wave * 64;
#pragma unroll
    for (int i = 0; i < 25; i += 5) {
        float4 q[5];
        int    gi[5];
#pragma unroll
        for (int u = 0; u < 5; ++u) {
            int g = (i + u) * 64 + lane;
            int row = g / 25;                 // const-divisor magic div
            int c4  = g - row * 25;
            gi[u] = g;
            q[u]  = ef[(long)widx[rbase + row] * 25 + c4];
        }
#pragma unroll
        for (int u = 0; u < 5; ++u) og[gi[u]] = q[u];
    }
}

// ---- finalize ----
__global__ void vq_final(const float* __restrict__ ws, float* __restrict__ out) {
    float t = 0.f;
#pragma unroll
    for (int w = 0; w < 8; ++w) t += ws[w];
    float mse = t / (float)((long)N_ROWS * D);
    out[(long)N_ROWS * D]     = mse;
    out[(long)N_ROWS * D + 1] = 0.25f * mse;
}

extern "C" void kernel_launch(void* const* d_in, const int* in_sizes, int n_in,
                              void* d_out, int out_size, void* d_ws, size_t ws_size,
                              hipStream_t stream) {
    const float* x   = (const float*)d_in[0];
    const float* emb = (const float*)d_in[1];
    float* out = (float*)d_out;
    float* ws  = (float*)d_ws;

    vq_init<<<KCODES, 64, 0, stream>>>(emb, ws);
    vq_main<<<N_ROWS / 512, 512, 0, stream>>>(x, emb, ws, out);
    vq_final<<<1, 1, 0, stream>>>(ws, out);
}